// Round 13
// baseline (1243.306 us; speedup 1.0000x reference)
//
#include <hip/hip_runtime.h>
#include <hip/hip_bf16.h>
#include <math.h>

#define N_ATOMS 50000
#define N_EDGES 1600000
#define FDIM 128
#define NB 25
#define CUTOFF_F 5.0f
#define PI_OVER_CUTOFF 0.6283185307179586f
#define NCH 196   // scan chunks of 256
#define NBLK 768  // persistent blocks for edge kernel (3/CU x 256 CU)
#define PERM_CAP (N_EDGES + 3 * N_ATOMS + 16)   // padded perm capacity (ints)

typedef __bf16 bf16x8 __attribute__((ext_vector_type(8)));
typedef float f32x4 __attribute__((ext_vector_type(4)));

__device__ __forceinline__ float swish_f(float v) {
    return v / (1.0f + __expf(-v));
}

// XOR swizzle on 16B slots (for 256B-stride hs rows).
#define SWZ(row) ((((row) & 7) ^ (((row) >> 3) & 1)) << 4)

// ---------------- sort-by-dst machinery (runs padded to x4) ----------------

__global__ void hist_kernel(const int* __restrict__ dst, int* __restrict__ count) {
    int i = blockIdx.x * 256 + threadIdx.x;
    if (i < N_EDGES) atomicAdd(&count[dst[i]], 1);
}

__global__ __launch_bounds__(256) void scan_chunk_kernel(
    const int* __restrict__ count, int* __restrict__ chunksum)
{
    __shared__ int red[256];
    const int t = threadIdx.x;
    const int i = blockIdx.x * 256 + t;
    red[t] = (i < N_ATOMS) ? ((count[i] + 3) & ~3) : 0;   // padded degree
    __syncthreads();
    for (int o = 128; o > 0; o >>= 1) {
        if (t < o) red[t] += red[t + o];
        __syncthreads();
    }
    if (t == 0) chunksum[blockIdx.x] = red[0];
}

// one block: exclusive scan of NCH chunk sums; total (E_pad) -> chunksum[NCH]
__global__ __launch_bounds__(256) void scan_base_kernel(int* __restrict__ chunksum) {
    __shared__ int sa[256], sb[256];
    const int t = threadIdx.x;
    int v = (t < NCH) ? chunksum[t] : 0;
    sa[t] = v;
    __syncthreads();
    int* cur = sa; int* nxt = sb;
    for (int o = 1; o < 256; o <<= 1) {
        int val = cur[t];
        if (t >= o) val += cur[t - o];
        nxt[t] = val;
        __syncthreads();
        int* tmp = cur; cur = nxt; nxt = tmp;
    }
    if (t < NCH) chunksum[t] = cur[t] - v;   // exclusive
    if (t == NCH - 1) chunksum[NCH] = cur[t];  // inclusive total = E_pad
}

__global__ __launch_bounds__(256) void scan_apply_kernel(
    const int* __restrict__ count, const int* __restrict__ chunksum,
    int* __restrict__ cursor)
{
    __shared__ int sa[256], sb[256];
    const int t = threadIdx.x;
    const int i = blockIdx.x * 256 + t;
    int v = (i < N_ATOMS) ? ((count[i] + 3) & ~3) : 0;    // padded degree
    sa[t] = v;
    __syncthreads();
    int* cur = sa; int* nxt = sb;
    for (int o = 1; o < 256; o <<= 1) {
        int val = cur[t];
        if (t >= o) val += cur[t - o];
        nxt[t] = val;
        __syncthreads();
        int* tmp = cur; cur = nxt; nxt = tmp;
    }
    if (i < N_ATOMS) cursor[i] = chunksum[blockIdx.x] + cur[t] - v;  // exclusive
}

__global__ void scatter_kernel(const int* __restrict__ dst, int* __restrict__ cursor,
                               int* __restrict__ perm) {
    int i = blockIdx.x * 256 + threadIdx.x;
    if (i < N_EDGES) {
        int d = dst[i];
        int p = atomicAdd(&cursor[d], 1);
        perm[p] = i;   // pad slots keep -1 from memset
    }
}

// ---------------- weight packing ----------------

__global__ void pack_b_kernel(const float* __restrict__ W, __bf16* __restrict__ out,
                              int K_eff, int KS)
{
    int idx = blockIdx.x * 256 + threadIdx.x;
    int total = KS * 8 * 64 * 8;
    if (idx >= total) return;
    int j  = idx & 7;
    int l  = (idx >> 3) & 63;
    int n  = (idx >> 9) & 7;
    int ks = idx >> 12;
    int k   = ks * 32 + ((l >> 4) << 3) + j;
    int col = (n << 4) + (l & 15);
    float v = (k < K_eff) ? W[k * FDIM + col] : 0.0f;
    out[idx] = (__bf16)v;
}

// ---------------- MFMA node GEMM (r12-proven) ----------------

__global__ __launch_bounds__(512, 2) void node_mfma_kernel(
    const float* __restrict__ A, const __bf16* __restrict__ wp,
    const float* __restrict__ bias,
    __bf16* __restrict__ out_bf, float* __restrict__ out_f32,
    int do_swish)
{
    __shared__ __bf16 ws_[16384];   // 32 KB packed B

    const int t = threadIdx.x;
    const int l = t & 63;
    const int w = t >> 6;
    const int lrow = l & 15;
    const int kgrp = l >> 4;

    {
        const int4* g = (const int4*)wp;
        int4* s = (int4*)ws_;
        for (int i = t; i < 2048; i += 512) s[i] = g[i];
    }
    float br[8];
    #pragma unroll
    for (int n = 0; n < 8; ++n) br[n] = bias ? bias[(n << 4) + lrow] : 0.0f;
    __syncthreads();

    const int tile = blockIdx.x * 8 + w;
    if (tile >= N_ATOMS / 16) return;
    const int row0 = tile << 4;

    bf16x8 af[4];
    const float* ap = A + (size_t)(row0 + lrow) * FDIM + (kgrp << 3);
    #pragma unroll
    for (int ks = 0; ks < 4; ++ks) {
        float4 lo = *(const float4*)(ap + (ks << 5));
        float4 hi = *(const float4*)(ap + (ks << 5) + 4);
        af[ks][0] = (__bf16)lo.x; af[ks][1] = (__bf16)lo.y;
        af[ks][2] = (__bf16)lo.z; af[ks][3] = (__bf16)lo.w;
        af[ks][4] = (__bf16)hi.x; af[ks][5] = (__bf16)hi.y;
        af[ks][6] = (__bf16)hi.z; af[ks][7] = (__bf16)hi.w;
    }

    const f32x4 zero = {0.f, 0.f, 0.f, 0.f};
    f32x4 acc[8];
    #pragma unroll
    for (int n = 0; n < 8; ++n) acc[n] = zero;

    #pragma unroll
    for (int ks = 0; ks < 4; ++ks) {
        bf16x8 bfr[8];
        #pragma unroll
        for (int n = 0; n < 8; ++n)
            bfr[n] = *(const bf16x8*)((const char*)ws_ + (((ks << 3) + n) << 10) + (l << 4));
        #pragma unroll
        for (int n = 0; n < 8; ++n)
            acc[n] = __builtin_amdgcn_mfma_f32_16x16x32_bf16(af[ks], bfr[n], acc[n], 0, 0, 0);
    }

    if (out_bf) {
        #pragma unroll
        for (int r = 0; r < 4; ++r) {
            bf16x8 o;
            #pragma unroll
            for (int n = 0; n < 8; ++n) {
                float v = acc[n][r] + br[n];
                if (do_swish) v = swish_f(v);
                o[n] = (__bf16)v;
            }
            *(bf16x8*)&out_bf[(size_t)(row0 + (kgrp << 2) + r) * FDIM + (lrow << 3)] = o;
        }
    } else {
        #pragma unroll
        for (int r = 0; r < 4; ++r) {
            int orow = row0 + (kgrp << 2) + r;
            #pragma unroll
            for (int n = 0; n < 8; ++n) {
                float v = acc[n][r] + br[n];
                if (do_swish) v = swish_f(v);
                out_f32[(size_t)orow * FDIM + (n << 4) + lrow] = v;
            }
        }
    }
}

// ---------------- persistent-wave MFMA edge kernel ----------------
// 768 blocks x 4 waves (3 blocks/CU, 12 waves/CU). Branch-free main loop:
// constant vmem-op count (18/lane/iter) so the compiler can emit counted
// vmcnt(N) and never drain in-flight atomics/prefetches. Runs padded to x4
// -> each lane's 4-edge window is single-dst -> exactly 8 atomics/lane/iter.

struct TileReg {
    float4 f0, f1;       // this lane's fij A-fragment data
    int   se_own, de_own;
    float rij_own;
};

__global__ __launch_bounds__(256, 3) void edge_kernel(
    const float* __restrict__ fij, const float* __restrict__ rij,
    const int* __restrict__ src, const int* __restrict__ dst,
    const int* __restrict__ perm, const int* __restrict__ epad_ptr,
    const __bf16* __restrict__ w1p, const float* __restrict__ b1,
    const __bf16* __restrict__ w2p, const float* __restrict__ b2,
    const __bf16* __restrict__ xb, float* __restrict__ agg)
{
    __shared__ __bf16 w2s[16384];       // 32 KB: W2 B-fragments
    __shared__ __bf16 hs[4][16 * 128];  // 16 KB: per-wave H tiles

    const int t = threadIdx.x;
    const int l = t & 63;
    const int w = t >> 6;               // 0..3
    const int lrow = l & 15;
    const int kgrp = l >> 4;

    {
        const int4* g2 = (const int4*)w2p;
        int4* s2 = (int4*)w2s;
        for (int i = t; i < 2048; i += 256) s2[i] = g2[i];
    }

    bf16x8 w1f[8];
    float b1r[8], b2r[8];
    #pragma unroll
    for (int n = 0; n < 8; ++n) {
        w1f[n] = *(const bf16x8*)(w1p + (((n << 6) + l) << 3));
        b1r[n] = b1[(n << 4) + lrow];
        b2r[n] = b2[(n << 4) + lrow];
    }
    __syncthreads();   // w2s ready; last barrier in the kernel

    __bf16* hw = hs[w];
    const f32x4 zero = {0.f, 0.f, 0.f, 0.f};

    const int Epad = *epad_ptr;          // multiple of 4
    const int NT = (Epad + 15) >> 4;     // 16-edge tiles (tail windows sentinel)

    const int gw = blockIdx.x * 4 + w;   // global wave id
    const int NW = NBLK * 4;

    // Branch-free gather: sentinel (pv<0) reads edge 0 with Cf forced 0.
    // kgrp==3 overreads 7 floats; they hit W1's zero-padded k>=25 rows.
    #define GATHER(T, pv) do { \
        int pve_ = ((pv) < 0) ? 0 : (pv); \
        const float* fp_ = fij + (size_t)pve_ * NB; \
        T.f0 = *(const float4*)(fp_ + (kgrp << 3)); \
        T.f1 = *(const float4*)(fp_ + (kgrp << 3) + 4); \
        T.se_own = src[pve_]; \
        T.de_own = dst[pve_]; \
        T.rij_own = ((pv) < 0) ? CUTOFF_F : rij[pve_]; \
    } while (0)

    TileReg cur, nxt;
    const int t0 = gw;
    {
        int i1 = (t0 < NT) ? t0 : (NT - 1);
        int pvA = perm[(i1 << 4) + lrow];
        GATHER(cur, pvA);
    }
    int pvB;
    {
        int i2 = (t0 + NW < NT) ? (t0 + NW) : (NT - 1);
        pvB = perm[(i2 << 4) + lrow];
    }

    for (int tb = t0; tb < NT; tb += NW) {
        const int tn = tb + NW;
        GATHER(nxt, pvB);                         // clamped-safe, always issued
        int i3 = tn + NW; i3 = (i3 < NT) ? i3 : (NT - 1);
        int pvC = perm[(i3 << 4) + lrow];

        // ---- epilogue prep: shfls (register-only) + xv loads early ----
        float Cf_own = (cur.rij_own < CUTOFF_F)
                     ? 0.5f * (__cosf(cur.rij_own * PI_OVER_CUTOFF) + 1.0f) : 0.0f;
        int se4[4]; float Cf[4];
        #pragma unroll
        for (int r = 0; r < 4; ++r) {
            se4[r] = __shfl(cur.se_own, (kgrp << 2) + r);
            Cf[r]  = __shfl(Cf_own, (kgrp << 2) + r);
        }
        int deW = __shfl(cur.de_own, kgrp << 2);  // window slot0 (always real in-run)
        bf16x8 xv4[4];
        #pragma unroll
        for (int r = 0; r < 4; ++r)
            xv4[r] = *(const bf16x8*)&xb[(size_t)se4[r] * FDIM + (lrow << 3)];

        // ---- A fragment from registers ----
        bf16x8 a;
        a[0] = (__bf16)cur.f0.x; a[1] = (__bf16)cur.f0.y;
        a[2] = (__bf16)cur.f0.z; a[3] = (__bf16)cur.f0.w;
        a[4] = (__bf16)cur.f1.x; a[5] = (__bf16)cur.f1.y;
        a[6] = (__bf16)cur.f1.z; a[7] = (__bf16)cur.f1.w;

        // ---- GEMM1: H = swish(fij_pad @ W1 + b1) -> hw (wave-local) ----
        #pragma unroll
        for (int n = 0; n < 8; ++n) {
            f32x4 h = __builtin_amdgcn_mfma_f32_16x16x32_bf16(a, w1f[n], zero, 0, 0, 0);
            #pragma unroll
            for (int r = 0; r < 4; ++r) {
                int hrow = (kgrp << 2) + r;           // 0..15
                float hv = swish_f(h[r] + b1r[n]);
                int byte = (hrow << 8) + (((n << 4) + lrow) << 1);
                byte ^= SWZ(hrow);
                *(__bf16*)((char*)hw + byte) = (__bf16)hv;
            }
        }
        // no barrier: hw is wave-local (same-wave DS ops are ordered)

        // ---- GEMM2: Wfilt = H @ W2 (B-frags batched from LDS) ----
        f32x4 acc[8];
        #pragma unroll
        for (int n = 0; n < 8; ++n) acc[n] = zero;

        #pragma unroll
        for (int ks = 0; ks < 4; ++ks) {
            int byte = (lrow << 8) + (ks << 6) + (kgrp << 4);
            byte ^= SWZ(lrow);
            bf16x8 a2 = *(const bf16x8*)((const char*)hw + byte);
            bf16x8 bfr[8];
            #pragma unroll
            for (int n = 0; n < 8; ++n)
                bfr[n] = *(const bf16x8*)((const char*)w2s + (((ks << 3) + n) << 10) + (l << 4));
            #pragma unroll
            for (int n = 0; n < 8; ++n)
                acc[n] = __builtin_amdgcn_mfma_f32_16x16x32_bf16(a2, bfr[n], acc[n], 0, 0, 0);
        }

        // ---- Epilogue: exactly 8 unconditional atomics per lane ----
        #pragma unroll
        for (int n = 0; n < 8; ++n) {
            float s = 0.f;
            #pragma unroll
            for (int r = 0; r < 4; ++r)
                s += (float)xv4[r][n] * (acc[n][r] + b2r[n]) * Cf[r];
            unsafeAtomicAdd(&agg[(size_t)deW * FDIM + (n << 4) + lrow], s);
        }

        pvB = pvC;
        cur = nxt;
    }
    #undef GATHER
}

extern "C" void kernel_launch(void* const* d_in, const int* in_sizes, int n_in,
                              void* d_out, int out_size, void* d_ws, size_t ws_size,
                              hipStream_t stream)
{
    const float* feat   = (const float*)d_in[0];
    const float* fij    = (const float*)d_in[1];
    const float* rij    = (const float*)d_in[2];
    const int*   src    = (const int*)d_in[3];
    const int*   dst    = (const int*)d_in[4];
    const float* W_in2f = (const float*)d_in[5];
    const float* W_f1   = (const float*)d_in[6];
    const float* b_f1   = (const float*)d_in[7];
    const float* W_f2   = (const float*)d_in[8];
    const float* b_f2   = (const float*)d_in[9];
    const float* W_out  = (const float*)d_in[10];
    const float* b_out  = (const float*)d_in[11];
    float* out = (float*)d_out;

    // ws layout, total ~20.3 MB (under proven 25.6 MB watermark)
    char* ws = (char*)d_ws;
    __bf16* xb       = (__bf16*)ws;                   // 12,800,000 B
    __bf16* w1p      = (__bf16*)(ws + 12800000);      //      8,192 B
    __bf16* w2p      = (__bf16*)(ws + 12808192);      //     32,768 B
    __bf16* winp     = (__bf16*)(ws + 12840960);      //     32,768 B
    __bf16* woutp    = (__bf16*)(ws + 12873728);      //     32,768 B
    int*    cursor   = (int*)(ws + 12906496);         //    200,000 B
    int*    count    = (int*)(ws + 13106496);         //    200,000 B
    int*    chunksum = (int*)(ws + 13306496);         //      1,024 B
    int*    perm     = (int*)(ws + 13307520);         //  7,000,064 B
    float*  agg      = out;                           // accumulate into d_out

    hipMemsetAsync(agg, 0, (size_t)N_ATOMS * FDIM * sizeof(float), stream);
    hipMemsetAsync(count, 0, N_ATOMS * sizeof(int), stream);
    hipMemsetAsync(perm, 0xFF, (size_t)PERM_CAP * sizeof(int), stream);  // -1 sentinels

    hist_kernel<<<(N_EDGES + 255) / 256, 256, 0, stream>>>(dst, count);
    scan_chunk_kernel<<<NCH, 256, 0, stream>>>(count, chunksum);
    scan_base_kernel<<<1, 256, 0, stream>>>(chunksum);
    scan_apply_kernel<<<NCH, 256, 0, stream>>>(count, chunksum, cursor);
    scatter_kernel<<<(N_EDGES + 255) / 256, 256, 0, stream>>>(dst, cursor, perm);

    pack_b_kernel<<<(4096 + 255) / 256, 256, 0, stream>>>(W_f1, w1p, NB, 1);
    pack_b_kernel<<<(16384 + 255) / 256, 256, 0, stream>>>(W_f2, w2p, 128, 4);
    pack_b_kernel<<<(16384 + 255) / 256, 256, 0, stream>>>(W_in2f, winp, 128, 4);
    pack_b_kernel<<<(16384 + 255) / 256, 256, 0, stream>>>(W_out, woutp, 128, 4);

    // x = feat @ W_in2f  -> xb (bf16, permuted)
    node_mfma_kernel<<<(N_ATOMS / 16 + 7) / 8, 512, 0, stream>>>(
        feat, winp, nullptr, xb, nullptr, 0);

    edge_kernel<<<NBLK, 256, 0, stream>>>(
        fij, rij, src, dst, perm, chunksum + NCH, w1p, b_f1, w2p, b_f2, xb, agg);

    // out = swish(agg @ W_out + b_out)  (in-place per 16-row tile)
    node_mfma_kernel<<<(N_ATOMS / 16 + 7) / 8, 512, 0, stream>>>(
        agg, woutp, b_out, nullptr, out, 1);
}

// Round 14
// 624.461 us; speedup vs baseline: 1.9910x; 1.9910x over previous
//
#include <hip/hip_runtime.h>
#include <hip/hip_bf16.h>
#include <math.h>

#define N_ATOMS 50000
#define N_EDGES 1600000
#define FDIM 128
#define NB 25
#define CUTOFF_F 5.0f
#define PI_OVER_CUTOFF 0.6283185307179586f
#define NCH 196   // scan chunks of 256
#define NBLK 512  // persistent blocks for edge kernel (2/CU x 256 CU)

typedef __bf16 bf16x8 __attribute__((ext_vector_type(8)));
typedef float f32x4 __attribute__((ext_vector_type(4)));

__device__ __forceinline__ float swish_f(float v) {
    return v / (1.0f + __expf(-v));
}

// XOR swizzle on 16B slots (for 256B-stride hs rows).
#define SWZ(row) ((((row) & 7) ^ (((row) >> 3) & 1)) << 4)

// ---------------- sort-by-dst machinery (r12-proven, unpadded) ----------------

__global__ void hist_kernel(const int* __restrict__ dst, int* __restrict__ count) {
    int i = blockIdx.x * 256 + threadIdx.x;
    if (i < N_EDGES) atomicAdd(&count[dst[i]], 1);
}

__global__ __launch_bounds__(256) void scan_chunk_kernel(
    const int* __restrict__ count, int* __restrict__ chunksum)
{
    __shared__ int red[256];
    const int t = threadIdx.x;
    const int i = blockIdx.x * 256 + t;
    red[t] = (i < N_ATOMS) ? count[i] : 0;
    __syncthreads();
    for (int o = 128; o > 0; o >>= 1) {
        if (t < o) red[t] += red[t + o];
        __syncthreads();
    }
    if (t == 0) chunksum[blockIdx.x] = red[0];
}

__global__ __launch_bounds__(256) void scan_base_kernel(int* __restrict__ chunksum) {
    __shared__ int sa[256], sb[256];
    const int t = threadIdx.x;
    int v = (t < NCH) ? chunksum[t] : 0;
    sa[t] = v;
    __syncthreads();
    int* cur = sa; int* nxt = sb;
    for (int o = 1; o < 256; o <<= 1) {
        int val = cur[t];
        if (t >= o) val += cur[t - o];
        nxt[t] = val;
        __syncthreads();
        int* tmp = cur; cur = nxt; nxt = tmp;
    }
    if (t < NCH) chunksum[t] = cur[t] - v;   // exclusive
}

__global__ __launch_bounds__(256) void scan_apply_kernel(
    const int* __restrict__ count, const int* __restrict__ chunksum,
    int* __restrict__ cursor)
{
    __shared__ int sa[256], sb[256];
    const int t = threadIdx.x;
    const int i = blockIdx.x * 256 + t;
    int v = (i < N_ATOMS) ? count[i] : 0;
    sa[t] = v;
    __syncthreads();
    int* cur = sa; int* nxt = sb;
    for (int o = 1; o < 256; o <<= 1) {
        int val = cur[t];
        if (t >= o) val += cur[t - o];
        nxt[t] = val;
        __syncthreads();
        int* tmp = cur; cur = nxt; nxt = tmp;
    }
    if (i < N_ATOMS) cursor[i] = chunksum[blockIdx.x] + cur[t] - v;  // exclusive
}

__global__ void scatter_kernel(const int* __restrict__ dst, int* __restrict__ cursor,
                               int* __restrict__ perm) {
    int i = blockIdx.x * 256 + threadIdx.x;
    if (i < N_EDGES) {
        int d = dst[i];
        int p = atomicAdd(&cursor[d], 1);
        perm[p] = i;
    }
}

// ---------------- weight packing ----------------

__global__ void pack_b_kernel(const float* __restrict__ W, __bf16* __restrict__ out,
                              int K_eff, int KS)
{
    int idx = blockIdx.x * 256 + threadIdx.x;
    int total = KS * 8 * 64 * 8;
    if (idx >= total) return;
    int j  = idx & 7;
    int l  = (idx >> 3) & 63;
    int n  = (idx >> 9) & 7;
    int ks = idx >> 12;
    int k   = ks * 32 + ((l >> 4) << 3) + j;
    int col = (n << 4) + (l & 15);
    float v = (k < K_eff) ? W[k * FDIM + col] : 0.0f;
    out[idx] = (__bf16)v;
}

// ---------------- MFMA node GEMM (r12-proven) ----------------

__global__ __launch_bounds__(512, 2) void node_mfma_kernel(
    const float* __restrict__ A, const __bf16* __restrict__ wp,
    const float* __restrict__ bias,
    __bf16* __restrict__ out_bf, float* __restrict__ out_f32,
    int do_swish)
{
    __shared__ __bf16 ws_[16384];   // 32 KB packed B

    const int t = threadIdx.x;
    const int l = t & 63;
    const int w = t >> 6;
    const int lrow = l & 15;
    const int kgrp = l >> 4;

    {
        const int4* g = (const int4*)wp;
        int4* s = (int4*)ws_;
        for (int i = t; i < 2048; i += 512) s[i] = g[i];
    }
    float br[8];
    #pragma unroll
    for (int n = 0; n < 8; ++n) br[n] = bias ? bias[(n << 4) + lrow] : 0.0f;
    __syncthreads();

    const int tile = blockIdx.x * 8 + w;
    if (tile >= N_ATOMS / 16) return;
    const int row0 = tile << 4;

    bf16x8 af[4];
    const float* ap = A + (size_t)(row0 + lrow) * FDIM + (kgrp << 3);
    #pragma unroll
    for (int ks = 0; ks < 4; ++ks) {
        float4 lo = *(const float4*)(ap + (ks << 5));
        float4 hi = *(const float4*)(ap + (ks << 5) + 4);
        af[ks][0] = (__bf16)lo.x; af[ks][1] = (__bf16)lo.y;
        af[ks][2] = (__bf16)lo.z; af[ks][3] = (__bf16)lo.w;
        af[ks][4] = (__bf16)hi.x; af[ks][5] = (__bf16)hi.y;
        af[ks][6] = (__bf16)hi.z; af[ks][7] = (__bf16)hi.w;
    }

    const f32x4 zero = {0.f, 0.f, 0.f, 0.f};
    f32x4 acc[8];
    #pragma unroll
    for (int n = 0; n < 8; ++n) acc[n] = zero;

    #pragma unroll
    for (int ks = 0; ks < 4; ++ks) {
        bf16x8 bfr[8];
        #pragma unroll
        for (int n = 0; n < 8; ++n)
            bfr[n] = *(const bf16x8*)((const char*)ws_ + (((ks << 3) + n) << 10) + (l << 4));
        #pragma unroll
        for (int n = 0; n < 8; ++n)
            acc[n] = __builtin_amdgcn_mfma_f32_16x16x32_bf16(af[ks], bfr[n], acc[n], 0, 0, 0);
    }

    if (out_bf) {
        #pragma unroll
        for (int r = 0; r < 4; ++r) {
            bf16x8 o;
            #pragma unroll
            for (int n = 0; n < 8; ++n) {
                float v = acc[n][r] + br[n];
                if (do_swish) v = swish_f(v);
                o[n] = (__bf16)v;
            }
            *(bf16x8*)&out_bf[(size_t)(row0 + (kgrp << 2) + r) * FDIM + (lrow << 3)] = o;
        }
    } else {
        #pragma unroll
        for (int r = 0; r < 4; ++r) {
            int orow = row0 + (kgrp << 2) + r;
            #pragma unroll
            for (int n = 0; n < 8; ++n) {
                float v = acc[n][r] + br[n];
                if (do_swish) v = swish_f(v);
                out_f32[(size_t)orow * FDIM + (n << 4) + lrow] = v;
            }
        }
    }
}

// ---------------- persistent-wave MFMA edge kernel (skewed pipeline) ----------------
// 512 blocks x 8 waves. Per iteration: gather(t+1) [issued first],
// GEMM2+epilogue of tile t-1 (hs written LAST iteration -> lgkm retired),
// GEMM1(t) overwrites hs (same-wave DS order: reads before writes).
// Epilogue = r12's uni fast path + run compression (atomic-locality-critical).

struct TileReg {
    float4 f0, f1;       // this lane's fij A-fragment data
    int   se_own, de_own;
    float rij_own;
};

__global__ __launch_bounds__(512, 2) void edge_kernel(
    const float* __restrict__ fij, const float* __restrict__ rij,
    const int* __restrict__ src, const int* __restrict__ dst,
    const int* __restrict__ perm,
    const __bf16* __restrict__ w1p, const float* __restrict__ b1,
    const __bf16* __restrict__ w2p, const float* __restrict__ b2,
    const __bf16* __restrict__ xb, float* __restrict__ agg)
{
    __shared__ __bf16 w2s[16384];       // 32 KB: W2 B-fragments
    __shared__ __bf16 hs[8][16 * 128];  // 32 KB: per-wave H tiles

    const int t = threadIdx.x;
    const int l = t & 63;
    const int w = t >> 6;               // 0..7
    const int lrow = l & 15;
    const int kgrp = l >> 4;

    {
        const int4* g2 = (const int4*)w2p;
        int4* s2 = (int4*)w2s;
        for (int i = t; i < 2048; i += 512) s2[i] = g2[i];
    }

    bf16x8 w1f[8];
    float b1r[8], b2r[8];
    #pragma unroll
    for (int n = 0; n < 8; ++n) {
        w1f[n] = *(const bf16x8*)(w1p + (((n << 6) + l) << 3));
        b1r[n] = b1[(n << 4) + lrow];
        b2r[n] = b2[(n << 4) + lrow];
    }
    __syncthreads();   // w2s ready; last barrier in the kernel

    __bf16* hw = hs[w];
    const f32x4 zero = {0.f, 0.f, 0.f, 0.f};

    const int gw = blockIdx.x * 8 + w;   // global wave id
    const int NW = NBLK * 8;
    const int NT = N_EDGES / 16;
    if (gw >= NT) return;

    #define GATHER(T, pv) do { \
        const float* fp_ = fij + (size_t)(pv) * NB; \
        if (kgrp < 3) { \
            T.f0 = *(const float4*)(fp_ + (kgrp << 3)); \
            T.f1 = *(const float4*)(fp_ + (kgrp << 3) + 4); \
        } else { \
            T.f0 = make_float4(fp_[24], 0.f, 0.f, 0.f); \
            T.f1 = make_float4(0.f, 0.f, 0.f, 0.f); \
        } \
        T.se_own = src[pv]; \
        T.de_own = dst[pv]; \
        T.rij_own = rij[pv]; \
    } while (0)

    // GEMM1: fij A-frag from T regs -> swish -> hw (bf16, swizzled)
    #define GEMM1_TO_HS(T) do { \
        bf16x8 a_; \
        a_[0] = (__bf16)T.f0.x; a_[1] = (__bf16)T.f0.y; \
        a_[2] = (__bf16)T.f0.z; a_[3] = (__bf16)T.f0.w; \
        a_[4] = (__bf16)T.f1.x; a_[5] = (__bf16)T.f1.y; \
        a_[6] = (__bf16)T.f1.z; a_[7] = (__bf16)T.f1.w; \
        _Pragma("unroll") \
        for (int n_ = 0; n_ < 8; ++n_) { \
            f32x4 h_ = __builtin_amdgcn_mfma_f32_16x16x32_bf16(a_, w1f[n_], zero, 0, 0, 0); \
            _Pragma("unroll") \
            for (int r_ = 0; r_ < 4; ++r_) { \
                int hrow_ = (kgrp << 2) + r_; \
                float hv_ = swish_f(h_[r_] + b1r[n_]); \
                int byte_ = (hrow_ << 8) + (((n_ << 4) + lrow) << 1); \
                byte_ ^= SWZ(hrow_); \
                *(__bf16*)((char*)hw + byte_) = (__bf16)hv_; \
            } \
        } \
    } while (0)

    // GEMM2 from hw into acc (declared by caller)
    #define GEMM2_FROM_HS(acc) do { \
        _Pragma("unroll") \
        for (int ks_ = 0; ks_ < 4; ++ks_) { \
            int byte_ = (lrow << 8) + (ks_ << 6) + (kgrp << 4); \
            byte_ ^= SWZ(lrow); \
            bf16x8 a2_ = *(const bf16x8*)((const char*)hw + byte_); \
            bf16x8 bfr_[8]; \
            _Pragma("unroll") \
            for (int n_ = 0; n_ < 8; ++n_) \
                bfr_[n_] = *(const bf16x8*)((const char*)w2s + (((ks_ << 3) + n_) << 10) + (l << 4)); \
            _Pragma("unroll") \
            for (int n_ = 0; n_ < 8; ++n_) \
                acc[n_] = __builtin_amdgcn_mfma_f32_16x16x32_bf16(a2_, bfr_[n_], acc[n_], 0, 0, 0); \
        } \
    } while (0)

    // r12 epilogue: uni fast path + run compression (needs T, acc, xv4, Cf, de4)
    #define EPILOGUE(T, acc, xv4, Cf, de4) do { \
        int d0_ = __shfl(T.de_own, 0); \
        bool uni_ = __all(T.de_own == d0_); \
        if (uni_) { \
            const size_t dbase_ = (size_t)d0_ * FDIM; \
            _Pragma("unroll") \
            for (int n_ = 0; n_ < 8; ++n_) { \
                float s_ = 0.f; \
                _Pragma("unroll") \
                for (int r_ = 0; r_ < 4; ++r_) \
                    s_ += (float)xv4[r_][n_] * (acc[n_][r_] + b2r[n_]) * Cf[r_]; \
                s_ += __shfl_xor(s_, 16); \
                s_ += __shfl_xor(s_, 32); \
                if (kgrp == 0) unsafeAtomicAdd(&agg[dbase_ + (n_ << 4) + lrow], s_); \
            } \
        } else { \
            const bool brk0_ = (de4[0] != de4[1]); \
            const bool brk1_ = (de4[1] != de4[2]); \
            const bool brk2_ = (de4[2] != de4[3]); \
            _Pragma("unroll") \
            for (int n_ = 0; n_ < 8; ++n_) { \
                int col_ = (n_ << 4) + lrow; \
                float m_[4]; \
                _Pragma("unroll") \
                for (int r_ = 0; r_ < 4; ++r_) \
                    m_[r_] = (float)xv4[r_][n_] * (acc[n_][r_] + b2r[n_]) * Cf[r_]; \
                float run_ = m_[0]; \
                if (brk0_) { unsafeAtomicAdd(&agg[(size_t)de4[0] * FDIM + col_], run_); run_ = 0.f; } \
                run_ += m_[1]; \
                if (brk1_) { unsafeAtomicAdd(&agg[(size_t)de4[1] * FDIM + col_], run_); run_ = 0.f; } \
                run_ += m_[2]; \
                if (brk2_) { unsafeAtomicAdd(&agg[(size_t)de4[2] * FDIM + col_], run_); run_ = 0.f; } \
                run_ += m_[3]; \
                unsafeAtomicAdd(&agg[(size_t)de4[3] * FDIM + col_], run_); \
            } \
        } \
    } while (0)

    // epilogue prep: shfl headers + xv loads (issued early, consumed late)
    #define PREP(T, se4, Cf, de4, xv4) do { \
        float Cfo_ = (T.rij_own < CUTOFF_F) \
                   ? 0.5f * (__cosf(T.rij_own * PI_OVER_CUTOFF) + 1.0f) : 0.0f; \
        _Pragma("unroll") \
        for (int r_ = 0; r_ < 4; ++r_) { \
            se4[r_] = __shfl(T.se_own, (kgrp << 2) + r_); \
            Cf[r_]  = __shfl(Cfo_, (kgrp << 2) + r_); \
            de4[r_] = __shfl(T.de_own, (kgrp << 2) + r_); \
        } \
        _Pragma("unroll") \
        for (int r_ = 0; r_ < 4; ++r_) \
            xv4[r_] = *(const bf16x8*)&xb[(size_t)se4[r_] * FDIM + (lrow << 3)]; \
    } while (0)

    TileReg TP, TC;

    // ---- prologue: tile gw -> GEMM1 into hw ----
    {
        int pv = perm[(gw << 4) + lrow];
        GATHER(TP, pv);
    }
    int nb0 = gw + NW; nb0 = (nb0 < NT) ? nb0 : (NT - 1);
    int pvB = perm[(nb0 << 4) + lrow];
    GEMM1_TO_HS(TP);

    // ---- main loop: iter tb does EPI(tb-NW) + GEMM1(tb) ----
    for (int tb = gw + NW; tb < NT; tb += NW) {
        GATHER(TC, pvB);                       // tile tb (perm loaded last iter)
        int nb = tb + NW; nb = (nb < NT) ? nb : (NT - 1);
        pvB = perm[(nb << 4) + lrow];

        int se4[4], de4[4]; float Cf[4]; bf16x8 xv4[4];
        PREP(TP, se4, Cf, de4, xv4);

        f32x4 acc[8];
        #pragma unroll
        for (int n = 0; n < 8; ++n) acc[n] = zero;
        GEMM2_FROM_HS(acc);                    // reads hs written LAST iter

        GEMM1_TO_HS(TC);                       // overwrites hs (DS-ordered after reads)

        EPILOGUE(TP, acc, xv4, Cf, de4);

        TP = TC;
    }

    // ---- tail: last tile's GEMM2 + epilogue ----
    {
        int se4[4], de4[4]; float Cf[4]; bf16x8 xv4[4];
        PREP(TP, se4, Cf, de4, xv4);
        f32x4 acc[8];
        #pragma unroll
        for (int n = 0; n < 8; ++n) acc[n] = zero;
        GEMM2_FROM_HS(acc);
        EPILOGUE(TP, acc, xv4, Cf, de4);
    }

    #undef GATHER
    #undef GEMM1_TO_HS
    #undef GEMM2_FROM_HS
    #undef EPILOGUE
    #undef PREP
}

extern "C" void kernel_launch(void* const* d_in, const int* in_sizes, int n_in,
                              void* d_out, int out_size, void* d_ws, size_t ws_size,
                              hipStream_t stream)
{
    const float* feat   = (const float*)d_in[0];
    const float* fij    = (const float*)d_in[1];
    const float* rij    = (const float*)d_in[2];
    const int*   src    = (const int*)d_in[3];
    const int*   dst    = (const int*)d_in[4];
    const float* W_in2f = (const float*)d_in[5];
    const float* W_f1   = (const float*)d_in[6];
    const float* b_f1   = (const float*)d_in[7];
    const float* W_f2   = (const float*)d_in[8];
    const float* b_f2   = (const float*)d_in[9];
    const float* W_out  = (const float*)d_in[10];
    const float* b_out  = (const float*)d_in[11];
    float* out = (float*)d_out;

    // ws layout, total 19,707,520 B
    char* ws = (char*)d_ws;
    __bf16* xb       = (__bf16*)ws;                   // 12,800,000 B
    __bf16* w1p      = (__bf16*)(ws + 12800000);      //      8,192 B
    __bf16* w2p      = (__bf16*)(ws + 12808192);      //     32,768 B
    __bf16* winp     = (__bf16*)(ws + 12840960);      //     32,768 B
    __bf16* woutp    = (__bf16*)(ws + 12873728);      //     32,768 B
    int*    cursor   = (int*)(ws + 12906496);         //    200,000 B
    int*    count    = (int*)(ws + 13106496);         //    200,000 B
    int*    chunksum = (int*)(ws + 13306496);         //      1,024 B
    int*    perm     = (int*)(ws + 13307520);         //  6,400,000 B
    float*  agg      = out;                           // accumulate into d_out

    hipMemsetAsync(agg, 0, (size_t)N_ATOMS * FDIM * sizeof(float), stream);
    hipMemsetAsync(count, 0, N_ATOMS * sizeof(int), stream);

    hist_kernel<<<(N_EDGES + 255) / 256, 256, 0, stream>>>(dst, count);
    scan_chunk_kernel<<<NCH, 256, 0, stream>>>(count, chunksum);
    scan_base_kernel<<<1, 256, 0, stream>>>(chunksum);
    scan_apply_kernel<<<NCH, 256, 0, stream>>>(count, chunksum, cursor);
    scatter_kernel<<<(N_EDGES + 255) / 256, 256, 0, stream>>>(dst, cursor, perm);

    pack_b_kernel<<<(4096 + 255) / 256, 256, 0, stream>>>(W_f1, w1p, NB, 1);
    pack_b_kernel<<<(16384 + 255) / 256, 256, 0, stream>>>(W_f2, w2p, 128, 4);
    pack_b_kernel<<<(16384 + 255) / 256, 256, 0, stream>>>(W_in2f, winp, 128, 4);
    pack_b_kernel<<<(16384 + 255) / 256, 256, 0, stream>>>(W_out, woutp, 128, 4);

    // x = feat @ W_in2f  -> xb (bf16, permuted)
    node_mfma_kernel<<<(N_ATOMS / 16 + 7) / 8, 512, 0, stream>>>(
        feat, winp, nullptr, xb, nullptr, 0);

    edge_kernel<<<NBLK, 512, 0, stream>>>(
        fij, rij, src, dst, perm, w1p, b_f1, w2p, b_f2, xb, agg);

    // out = swish(agg @ W_out + b_out)  (in-place per 16-row tile)
    node_mfma_kernel<<<(N_ATOMS / 16 + 7) / 8, 512, 0, stream>>>(
        agg, woutp, b_out, nullptr, out, 1);
}